// Round 17
// baseline (130.561 us; speedup 1.0000x reference)
//
#include <hip/hip_runtime.h>
#include <math.h>

typedef unsigned short u16;
typedef __attribute__((ext_vector_type(8))) short short8;
typedef __attribute__((ext_vector_type(4))) short short4v;
typedef __attribute__((ext_vector_type(4))) float f32x4;

static __device__ __forceinline__ u16 f2bf(float f) {
  union { float f; unsigned u; } v; v.f = f;
  unsigned u = v.u;
  return (u16)((u + 0x7FFFu + ((u >> 16) & 1u)) >> 16);
}
static __device__ __forceinline__ float bf2f(u16 u) {
  union { unsigned u; float f; } v; v.u = ((unsigned)u) << 16;
  return v.f;
}
static __device__ __forceinline__ f32x4 mfma16(short8 a, short8 b, f32x4 c) {
  return __builtin_amdgcn_mfma_f32_16x16x32_bf16(a, b, c, 0, 0, 0);
}

// ---------------------------------------------------------------------------
// prep: WtV/outwT bf16 transposed [n][k]; Wcat f32 (256x288) + bcat. (proven)
// ---------------------------------------------------------------------------
__global__ void prep_weights(const float* __restrict__ vw,
                             const float* __restrict__ offw, const float* __restrict__ attnw,
                             const float* __restrict__ offb, const float* __restrict__ attnb,
                             const float* __restrict__ outw,
                             u16* __restrict__ WtV, u16* __restrict__ outwT,
                             float* __restrict__ Wcat, float* __restrict__ bcat) {
  int idx = blockIdx.x * 256 + threadIdx.x;  // grid 288 -> 73728
  if (idx < 65536) {
    int n = idx >> 8, k = idx & 255;
    WtV[idx] = f2bf(vw[k * 256 + n]);
    outwT[idx] = f2bf(outw[k * 256 + n]);
  }
  if (idx < 73728) {
    int kk = idx / 288, nn = idx % 288;
    Wcat[idx] = (nn < 192) ? offw[kk * 192 + nn] : attnw[kk * 96 + (nn - 192)];
  }
  if (idx < 288) bcat[idx] = (idx < 192) ? offb[idx] : attnb[idx - 192];
}

// ---------------------------------------------------------------------------
// Fat kernel v2 (proven R16): blocks [0,450) offsets fp32 GEMM 32x96;
// blocks [450,2498) grid-stride f32->bf16 convert.
// ---------------------------------------------------------------------------
#define NOFFB 450
#define NCVT 2048
__global__ __launch_bounds__(256) void fat_cvt_off2(
    const float* __restrict__ ehs, u16* __restrict__ A16,
    const float* __restrict__ hidden, const float* __restrict__ Wcat,
    const float* __restrict__ bcat, float* __restrict__ offaw) {
  const int tid = threadIdx.x;
  if (blockIdx.x >= NOFFB) {
    const size_t n4 = 8601600;  // 34406400 / 4
    const size_t stride = (size_t)NCVT * 256;
    for (size_t idx = (size_t)(blockIdx.x - NOFFB) * 256 + tid; idx < n4; idx += stride) {
      float4 v = ((const float4*)ehs)[idx];
      short4v o;
      o[0] = (short)f2bf(v.x);
      o[1] = (short)f2bf(v.y);
      o[2] = (short)f2bf(v.z);
      o[3] = (short)f2bf(v.w);
      ((short4v*)A16)[idx] = o;
    }
    return;
  }
  __shared__ float As[8][33];
  __shared__ float Bs[8][100];
  const int bm = blockIdx.x / 3, bn = blockIdx.x % 3;
  const int m0 = bm * 32, n0 = bn * 96;
  const int tr = tid >> 4, tc = tid & 15;

  float acc[2][6];
#pragma unroll
  for (int i = 0; i < 2; i++)
#pragma unroll
    for (int j = 0; j < 6; j++) acc[i][j] = 0.f;

  const int sar = tid >> 3, sak = tid & 7;
  const int sbk = tid / 24, sbc = (tid % 24) * 4;

  for (int k0 = 0; k0 < 256; k0 += 8) {
    float a1 = hidden[(size_t)(m0 + sar) * 256 + k0 + sak];
    float4 b4 = make_float4(0.f, 0.f, 0.f, 0.f);
    if (tid < 192)
      b4 = *(const float4*)(Wcat + (size_t)(k0 + sbk) * 288 + n0 + sbc);
    __syncthreads();
    As[sak][sar] = a1;
    if (tid < 192) *(float4*)&Bs[sbk][sbc] = b4;
    __syncthreads();
#pragma unroll
    for (int k = 0; k < 8; k++) {
      float ar[2], br[6];
#pragma unroll
      for (int i = 0; i < 2; i++) ar[i] = As[k][tr * 2 + i];
#pragma unroll
      for (int j = 0; j < 6; j++) br[j] = Bs[k][tc * 6 + j];
#pragma unroll
      for (int i = 0; i < 2; i++)
#pragma unroll
        for (int j = 0; j < 6; j++) acc[i][j] = fmaf(ar[i], br[j], acc[i][j]);
    }
  }

#pragma unroll
  for (int i = 0; i < 2; i++) {
    const int row = m0 + tr * 2 + i;
    float* Crow = offaw + (size_t)row * 288 + n0 + tc * 6;
#pragma unroll
    for (int j = 0; j < 6; j += 2) {
      float2 o;
      o.x = acc[i][j + 0] + bcat[n0 + tc * 6 + j + 0];
      o.y = acc[i][j + 1] + bcat[n0 + tc * 6 + j + 1];
      *(float2*)(Crow + j) = o;
    }
  }
}

// ---------------------------------------------------------------------------
// Value GEMM, all-bf16, global_load_lds staging (m97 structure). Proven R13.
// ---------------------------------------------------------------------------
__global__ __launch_bounds__(256) void gemm_value_g16(
    const u16* __restrict__ A16, const u16* __restrict__ Wt,
    const float* __restrict__ bias, u16* __restrict__ C) {
  const int m0 = blockIdx.y * 128, n0 = blockIdx.x * 128;
  __shared__ u16 smem[16384];   // 32 KiB
  u16* const As = smem;
  u16* const Bs = smem + 8192;
  const int tid = threadIdx.x, lane = tid & 63, w = tid >> 6;
  const int wrow = w >> 1, wcol = w & 1;

  f32x4 acc[4][4];
#pragma unroll
  for (int i = 0; i < 4; i++)
#pragma unroll
    for (int j = 0; j < 4; j++) acc[i][j] = (f32x4){0.f, 0.f, 0.f, 0.f};

#pragma unroll
  for (int t = 0; t < 4; t++) {
    const int k0 = t * 64;
#pragma unroll
    for (int c = 0; c < 4; c++) {
      const int G = c * 256 + w * 64 + lane;
      const int row = G >> 3, gr = G & 7;
      const int ksw = (gr * 8) ^ ((row & 7) * 8);
      __builtin_amdgcn_global_load_lds(
          A16 + (size_t)(m0 + row) * 256 + k0 + ksw,
          As + c * 2048 + w * 512, 16, 0, 0);
      __builtin_amdgcn_global_load_lds(
          Wt + (size_t)(n0 + row) * 256 + k0 + ksw,
          Bs + c * 2048 + w * 512, 16, 0, 0);
    }
    __syncthreads();

#pragma unroll
    for (int kk = 0; kk < 64; kk += 32) {
      const int kb = kk + ((lane >> 4) << 3);
      short8 af[4], bfr[4];
#pragma unroll
      for (int i = 0; i < 4; i++) {
        const int row = wrow * 64 + i * 16 + (lane & 15);
        af[i] = *(const short8*)&As[row * 64 + (kb ^ ((row & 7) * 8))];
      }
#pragma unroll
      for (int j = 0; j < 4; j++) {
        const int nr = wcol * 64 + j * 16 + (lane & 15);
        bfr[j] = *(const short8*)&Bs[nr * 64 + (kb ^ ((nr & 7) * 8))];
      }
#pragma unroll
      for (int i = 0; i < 4; i++)
#pragma unroll
        for (int j = 0; j < 4; j++)
          acc[i][j] = mfma16(af[i], bfr[j], acc[i][j]);
    }
    __syncthreads();
  }

  u16* const Cs = smem;
#pragma unroll
  for (int i = 0; i < 4; i++) {
#pragma unroll
    for (int j = 0; j < 4; j++) {
      const int col = wcol * 64 + j * 16 + (lane & 15);
      const float bc = bias[n0 + col];
#pragma unroll
      for (int r = 0; r < 4; r++) {
        const int row = wrow * 64 + i * 16 + ((lane >> 4) << 2) + r;
        Cs[row * 128 + (col ^ ((row & 7) * 8))] = f2bf(acc[i][j][r] + bc);
      }
    }
  }
  __syncthreads();
#pragma unroll
  for (int p = 0; p < 8; p++) {
    const int row = (tid >> 4) + p * 16;
    const int g = (tid & 15) * 8;
    *(short8*)(C + (size_t)(m0 + row) * 256 + n0 + g) =
        *(const short8*)&Cs[row * 128 + (g ^ ((row & 7) * 8))];
  }
}

// ---------------------------------------------------------------------------
// Fallback value GEMM (R9 bk32) if ws too small.
// ---------------------------------------------------------------------------
__global__ __launch_bounds__(256) void gemm_value_bk32(
    const float* __restrict__ A, const u16* __restrict__ Wt,
    const float* __restrict__ bias, u16* __restrict__ C) {
  const int m0 = blockIdx.y * 128, n0 = blockIdx.x * 128;
  __shared__ u16 smem[16384];
  u16* As = smem;
  u16* Bs = smem + 4096;
  const int tid = threadIdx.x, lane = tid & 63, w = tid >> 6;
  const int wrow = w >> 1, wcol = w & 1;
  const int ar = tid >> 3, ac4 = (tid & 7) * 4;
  const int bn = tid >> 1, bc16 = (tid & 1) * 16;
  const int bswz = (bn & 3) * 8;

  f32x4 acc[4][4];
#pragma unroll
  for (int i = 0; i < 4; i++)
#pragma unroll
    for (int j = 0; j < 4; j++) acc[i][j] = (f32x4){0.f, 0.f, 0.f, 0.f};

  float4 av[4];
  short8 bv[2];
#pragma unroll
  for (int p = 0; p < 4; p++)
    av[p] = *(const float4*)(A + (size_t)(m0 + ar + p * 32) * 256 + ac4);
#pragma unroll
  for (int j = 0; j < 2; j++)
    bv[j] = *(const short8*)(Wt + (size_t)(n0 + bn) * 256 + ((bc16 + 8 * j) ^ bswz));

#pragma unroll
  for (int t = 0; t < 8; t++) {
    __syncthreads();
#pragma unroll
    for (int p = 0; p < 4; p++) {
      const int row = ar + p * 32;
      short4v sv;
      sv[0] = (short)f2bf(av[p].x);
      sv[1] = (short)f2bf(av[p].y);
      sv[2] = (short)f2bf(av[p].z);
      sv[3] = (short)f2bf(av[p].w);
      *(short4v*)&As[row * 32 + (ac4 ^ ((row & 3) * 8))] = sv;
    }
#pragma unroll
    for (int j = 0; j < 2; j++)
      *(short8*)&Bs[bn * 32 + bc16 + 8 * j] = bv[j];
    __syncthreads();

    if (t < 7) {
      const int k0 = (t + 1) * 32;
#pragma unroll
      for (int p = 0; p < 4; p++)
        av[p] = *(const float4*)(A + (size_t)(m0 + ar + p * 32) * 256 + k0 + ac4);
#pragma unroll
      for (int j = 0; j < 2; j++)
        bv[j] = *(const short8*)(Wt + (size_t)(n0 + bn) * 256 + k0 + ((bc16 + 8 * j) ^ bswz));
    }

    const int kb = (lane >> 4) * 8;
    short8 af[4], bfr[4];
#pragma unroll
    for (int i = 0; i < 4; i++) {
      const int row = wrow * 64 + i * 16 + (lane & 15);
      af[i] = *(const short8*)&As[row * 32 + (kb ^ ((row & 3) * 8))];
    }
#pragma unroll
    for (int j = 0; j < 4; j++) {
      const int nr = wcol * 64 + j * 16 + (lane & 15);
      bfr[j] = *(const short8*)&Bs[nr * 32 + (kb ^ ((nr & 3) * 8))];
    }
#pragma unroll
    for (int i = 0; i < 4; i++)
#pragma unroll
      for (int j = 0; j < 4; j++)
        acc[i][j] = mfma16(af[i], bfr[j], acc[i][j]);
  }

  __syncthreads();
  u16* Cs = smem;
#pragma unroll
  for (int i = 0; i < 4; i++) {
#pragma unroll
    for (int j = 0; j < 4; j++) {
      const int col = wcol * 64 + j * 16 + (lane & 15);
      const float bc = bias[n0 + col];
#pragma unroll
      for (int r = 0; r < 4; r++) {
        const int row = wrow * 64 + i * 16 + ((lane >> 4) << 2) + r;
        Cs[row * 128 + (col ^ ((row & 7) * 8))] = f2bf(acc[i][j][r] + bc);
      }
    }
  }
  __syncthreads();
#pragma unroll
  for (int p = 0; p < 8; p++) {
    const int row = (tid >> 4) + p * 16;
    const int g = (tid & 15) * 8;
    *(short8*)(C + (size_t)(m0 + row) * 256 + n0 + g) =
        *(const short8*)&Cs[row * 128 + (g ^ ((row & 7) * 8))];
  }
}

// ---------------------------------------------------------------------------
// fp32 GEMM standalone (fallback path only).
// ---------------------------------------------------------------------------
__global__ __launch_bounds__(256) void gemm_f32(
    const float* __restrict__ A, const float* __restrict__ W,
    const float* __restrict__ bias, float* __restrict__ C,
    int M, int N, int K) {
  __shared__ float As[8][132];
  __shared__ float Bs[8][132];
  const int tid = threadIdx.x;
  const int bm = blockIdx.y, bn = blockIdx.x;
  const int tr = tid >> 4, tc = tid & 15;

  float acc[8][8];
#pragma unroll
  for (int i = 0; i < 8; i++)
#pragma unroll
    for (int j = 0; j < 8; j++) acc[i][j] = 0.f;

  int arow = bm * 128 + (tid >> 1);
  int arow_c = arow < M ? arow : (M - 1);
  const float* Aptr = A + (size_t)arow_c * K + ((tid & 1) << 2);
  int bcol = bn * 128 + ((tid & 31) << 2);
  const bool bvalid = bcol < N;
  const float* Wptr = W + (size_t)(tid >> 5) * N + bcol;

  for (int k0 = 0; k0 < K; k0 += 8) {
    float4 av = *(const float4*)(Aptr + k0);
    float4 bv = bvalid ? *(const float4*)(Wptr + (size_t)k0 * N)
                       : make_float4(0.f, 0.f, 0.f, 0.f);
    __syncthreads();
    As[(tid & 1) * 4 + 0][tid >> 1] = av.x;
    As[(tid & 1) * 4 + 1][tid >> 1] = av.y;
    As[(tid & 1) * 4 + 2][tid >> 1] = av.z;
    As[(tid & 1) * 4 + 3][tid >> 1] = av.w;
    *(float4*)&Bs[tid >> 5][(tid & 31) << 2] = bv;
    __syncthreads();
#pragma unroll
    for (int k = 0; k < 8; k++) {
      float ar[8], br[8];
      *(float4*)&ar[0] = *(const float4*)&As[k][tr * 8];
      *(float4*)&ar[4] = *(const float4*)&As[k][tr * 8 + 4];
      *(float4*)&br[0] = *(const float4*)&Bs[k][tc * 8];
      *(float4*)&br[4] = *(const float4*)&Bs[k][tc * 8 + 4];
#pragma unroll
      for (int i = 0; i < 8; i++)
#pragma unroll
        for (int j = 0; j < 8; j++) acc[i][j] = fmaf(ar[i], br[j], acc[i][j]);
    }
  }

#pragma unroll
  for (int i = 0; i < 8; i++) {
    int row = bm * 128 + tr * 8 + i;
    if (row >= M) continue;
    float* Crow = C + (size_t)row * N;
#pragma unroll
    for (int j = 0; j < 8; j += 4) {
      int col = bn * 128 + tc * 8 + j;
      if (col < N) {
        float4 o;
        o.x = acc[i][j + 0] + bias[col + 0];
        o.y = acc[i][j + 1] + bias[col + 1];
        o.z = acc[i][j + 2] + bias[col + 2];
        o.w = acc[i][j + 3] + bias[col + 3];
        *(float4*)(Crow + col) = o;
      }
    }
  }
}

// ---------------------------------------------------------------------------
// Branch-free sampling, 8 channels/lane (short8 gathers), 8 queries/block,
// XCD swizzle: slot P = blockIdx&7 serves batches {2P,2P+1}.
// grid 608 = 8 x 76: t<75 -> bq0 = P*600 + t*8; t=75 -> pad rows 4800+P*8.
// ---------------------------------------------------------------------------
__global__ __launch_bounds__(256) void ms_deform_fused(
    const u16* __restrict__ value, const float* __restrict__ offaw,
    const float* __restrict__ refp, u16* __restrict__ attn_out) {
  const int tid = threadIdx.x;
  const int P = blockIdx.x & 7;
  const int t = blockIdx.x >> 3;     // 0..75
  const int bq0 = (t < 75) ? (P * 600 + t * 8) : (4800 + P * 8);
  const int bq = bq0 + (tid >> 5);
  const int h = (tid >> 2) & 7;
  const int d8 = (tid & 3) * 8;
  u16* outp = attn_out + (size_t)bq * 256 + h * 32 + d8;
  if (bq >= 4800) {
    *(short8*)outp = (short8){0, 0, 0, 0, 0, 0, 0, 0};
    return;
  }
  const int b = bq / 300;
  const float* row = offaw + (size_t)bq * 288;

  float lg[12];
#pragma unroll
  for (int j = 0; j < 12; j++) lg[j] = row[192 + h * 12 + j];
  float m = lg[0];
#pragma unroll
  for (int j = 1; j < 12; j++) m = fmaxf(m, lg[j]);
  float s = 0.f;
#pragma unroll
  for (int j = 0; j < 12; j++) { lg[j] = __expf(lg[j] - m); s += lg[j]; }
  const float inv = 1.f / s;

  const int lvlW[3] = {80, 40, 20};
  const int lvlS[3] = {0, 6400, 8000};
  const float* ref = refp + (size_t)bq * 12;
  float acc[8];
#pragma unroll
  for (int e = 0; e < 8; e++) acc[e] = 0.f;

#pragma unroll
  for (int l = 0; l < 3; l++) {
    const int Ws = lvlW[l];
    const float r0 = ref[l * 4 + 0], r1 = ref[l * 4 + 1];
    const float r2 = ref[l * 4 + 2], r3 = ref[l * 4 + 3];
    const u16* vbase = value + ((size_t)(b * 8400 + lvlS[l]) * 256) + h * 32 + d8;
#pragma unroll
    for (int p = 0; p < 4; p++) {
      const float ox = row[h * 24 + l * 8 + p * 2 + 0];
      const float oy = row[h * 24 + l * 8 + p * 2 + 1];
      const float x = (r0 + ox * 0.125f * r2) * (float)Ws - 0.5f;
      const float y = (r1 + oy * 0.125f * r3) * (float)Ws - 0.5f;
      const float x0f = floorf(x), y0f = floorf(y);
      const float wx = x - x0f, wy = y - y0f;
      const int x0 = (int)x0f, y0 = (int)y0f;
      const int x0c = min(max(x0, 0), Ws - 1), x1c = min(max(x0 + 1, 0), Ws - 1);
      const int y0c = min(max(y0, 0), Ws - 1), y1c = min(max(y0 + 1, 0), Ws - 1);
      const float fx0 = ((unsigned)x0 < (unsigned)Ws) ? 1.f : 0.f;
      const float fx1 = ((unsigned)(x0 + 1) < (unsigned)Ws) ? 1.f : 0.f;
      const float fy0 = ((unsigned)y0 < (unsigned)Ws) ? 1.f : 0.f;
      const float fy1 = ((unsigned)(y0 + 1) < (unsigned)Ws) ? 1.f : 0.f;
      const short8 v00 = *(const short8*)(vbase + (size_t)(y0c * Ws + x0c) * 256);
      const short8 v01 = *(const short8*)(vbase + (size_t)(y0c * Ws + x1c) * 256);
      const short8 v10 = *(const short8*)(vbase + (size_t)(y1c * Ws + x0c) * 256);
      const short8 v11 = *(const short8*)(vbase + (size_t)(y1c * Ws + x1c) * 256);
      const float pw = lg[l * 4 + p] * inv;
      const float w00 = (1.f - wx) * (1.f - wy) * fy0 * fx0 * pw;
      const float w01 = wx * (1.f - wy) * fy0 * fx1 * pw;
      const float w10 = (1.f - wx) * wy * fy1 * fx0 * pw;
      const float w11 = wx * wy * fy1 * fx1 * pw;
#pragma unroll
      for (int e = 0; e < 8; e++) {
        acc[e] = fmaf(w00, bf2f((u16)v00[e]), acc[e]);
        acc[e] = fmaf(w01, bf2f((u16)v01[e]), acc[e]);
        acc[e] = fmaf(w10, bf2f((u16)v10[e]), acc[e]);
        acc[e] = fmaf(w11, bf2f((u16)v11[e]), acc[e]);
      }
    }
  }
  short8 o;
#pragma unroll
  for (int e = 0; e < 8; e++) o[e] = (short)f2bf(acc[e]);
  *(short8*)outp = o;
}

// ---------------------------------------------------------------------------
// Out-proj streaming GEMM (proven R6).
// ---------------------------------------------------------------------------
__global__ __launch_bounds__(256) void gemm_out_stream(
    const u16* __restrict__ A, const u16* __restrict__ Wt,
    const float* __restrict__ bias, float* __restrict__ C) {
  const int tid = threadIdx.x, lane = tid & 63, w = tid >> 6;
  const int m0 = (blockIdx.x * 2 + (w >> 1)) * 64;
  const int n0 = (w & 1) * 128;
  const int r16 = lane & 15, kq = lane >> 4, kh8 = kq * 8;

  f32x4 acc[4][8];
#pragma unroll
  for (int i = 0; i < 4; i++)
#pragma unroll
    for (int j = 0; j < 8; j++) acc[i][j] = (f32x4){0.f, 0.f, 0.f, 0.f};

  const u16* ab = A + (size_t)(m0 + r16) * 256 + kh8;
  const u16* bb = Wt + (size_t)(n0 + r16) * 256 + kh8;

#pragma unroll 2
  for (int ks = 0; ks < 8; ks++) {
    const int kk = ks * 32;
    short8 bfr[8], afr[4];
#pragma unroll
    for (int j = 0; j < 8; j++)
      bfr[j] = *(const short8*)(bb + (size_t)(j * 16) * 256 + kk);
#pragma unroll
    for (int i = 0; i < 4; i++)
      afr[i] = *(const short8*)(ab + (size_t)(i * 16) * 256 + kk);
#pragma unroll
    for (int i = 0; i < 4; i++)
#pragma unroll
      for (int j = 0; j < 8; j++)
        acc[i][j] = mfma16(afr[i], bfr[j], acc[i][j]);
  }

  if (m0 >= 4800) return;
#pragma unroll
  for (int i = 0; i < 4; i++)
#pragma unroll
    for (int j = 0; j < 8; j++) {
      const int col = n0 + j * 16 + r16;
      const float bc = bias[col];
#pragma unroll
      for (int r = 0; r < 4; r++) {
        const int row = m0 + i * 16 + kq * 4 + r;
        C[(size_t)row * 256 + col] = acc[i][j][r] + bc;
      }
    }
}

extern "C" void kernel_launch(void* const* d_in, const int* in_sizes, int n_in,
                              void* d_out, int out_size, void* d_ws, size_t ws_size,
                              hipStream_t stream) {
  const float* hidden = (const float*)d_in[0];
  const float* ehs    = (const float*)d_in[1];
  const float* refp   = (const float*)d_in[2];
  const float* vw     = (const float*)d_in[3];
  const float* vb     = (const float*)d_in[4];
  const float* offw   = (const float*)d_in[5];
  const float* offb   = (const float*)d_in[6];
  const float* attnw  = (const float*)d_in[7];
  const float* attnb  = (const float*)d_in[8];
  const float* outw   = (const float*)d_in[9];
  const float* outb   = (const float*)d_in[10];
  float* out = (float*)d_out;

  u16* value = (u16*)d_ws;                 // 34406400 u16
  u16* attn  = value + 34406400;           // 1245184 u16
  u16* WtV   = attn + 1245184;             // 65536
  u16* outwT = WtV + 65536;                // 65536
  float* Wcat  = (float*)(outwT + 65536);  // 73728 f32
  float* bcat  = Wcat + 73728;             // 512
  float* offaw = bcat + 512;               // 1382400
  u16* A16 = (u16*)(offaw + 1382400);      // 34406400 u16
  const size_t need = (size_t)((char*)(A16 + 34406400) - (char*)d_ws);

  prep_weights<<<288, 256, 0, stream>>>(vw, offw, attnw, offb, attnb, outw,
                                        WtV, outwT, Wcat, bcat);
  if (ws_size >= need) {
    fat_cvt_off2<<<NOFFB + NCVT, 256, 0, stream>>>(ehs, A16, hidden, Wcat, bcat, offaw);
    gemm_value_g16<<<dim3(2, 1050), 256, 0, stream>>>(A16, WtV, vb, value);
  } else {
    gemm_f32<<<dim3(3, 38), 256, 0, stream>>>(hidden, Wcat, bcat, offaw, 4800, 288, 256);
    gemm_value_bk32<<<dim3(2, 1050), 256, 0, stream>>>(ehs, WtV, vb, value);
  }
  ms_deform_fused<<<608, 256, 0, stream>>>(value, offaw, refp, attn);
  gemm_out_stream<<<38, 256, 0, stream>>>(attn, outwT, outb, out);
}

// Round 18
// 128.859 us; speedup vs baseline: 1.0132x; 1.0132x over previous
//
#include <hip/hip_runtime.h>
#include <math.h>

typedef unsigned short u16;
typedef __attribute__((ext_vector_type(8))) short short8;
typedef __attribute__((ext_vector_type(4))) short short4v;
typedef __attribute__((ext_vector_type(4))) float f32x4;

static __device__ __forceinline__ u16 f2bf(float f) {
  union { float f; unsigned u; } v; v.f = f;
  unsigned u = v.u;
  return (u16)((u + 0x7FFFu + ((u >> 16) & 1u)) >> 16);
}
static __device__ __forceinline__ float bf2f(u16 u) {
  union { unsigned u; float f; } v; v.u = ((unsigned)u) << 16;
  return v.f;
}
static __device__ __forceinline__ f32x4 mfma16(short8 a, short8 b, f32x4 c) {
  return __builtin_amdgcn_mfma_f32_16x16x32_bf16(a, b, c, 0, 0, 0);
}

// ---------------------------------------------------------------------------
// prep: WtV/outwT bf16 transposed [n][k]; Wcat f32 (256x288) + bcat. (proven)
// ---------------------------------------------------------------------------
__global__ void prep_weights(const float* __restrict__ vw,
                             const float* __restrict__ offw, const float* __restrict__ attnw,
                             const float* __restrict__ offb, const float* __restrict__ attnb,
                             const float* __restrict__ outw,
                             u16* __restrict__ WtV, u16* __restrict__ outwT,
                             float* __restrict__ Wcat, float* __restrict__ bcat) {
  int idx = blockIdx.x * 256 + threadIdx.x;  // grid 288 -> 73728
  if (idx < 65536) {
    int n = idx >> 8, k = idx & 255;
    WtV[idx] = f2bf(vw[k * 256 + n]);
    outwT[idx] = f2bf(outw[k * 256 + n]);
  }
  if (idx < 73728) {
    int kk = idx / 288, nn = idx % 288;
    Wcat[idx] = (nn < 192) ? offw[kk * 192 + nn] : attnw[kk * 96 + (nn - 192)];
  }
  if (idx < 288) bcat[idx] = (idx < 192) ? offb[idx] : attnb[idx - 192];
}

// ---------------------------------------------------------------------------
// Fat kernel v3: 2048 blocks total (450 offsets GEMM + 1598 convert) so the
// whole grid is resident in ONE scheduling round (256 CU x 8 blocks).
// ---------------------------------------------------------------------------
#define NOFFB 450
#define NCVT 1598
__global__ __launch_bounds__(256) void fat_cvt_off2(
    const float* __restrict__ ehs, u16* __restrict__ A16,
    const float* __restrict__ hidden, const float* __restrict__ Wcat,
    const float* __restrict__ bcat, float* __restrict__ offaw) {
  const int tid = threadIdx.x;
  if (blockIdx.x >= NOFFB) {
    const size_t n4 = 8601600;  // 34406400 / 4
    const size_t stride = (size_t)NCVT * 256;
    for (size_t idx = (size_t)(blockIdx.x - NOFFB) * 256 + tid; idx < n4; idx += stride) {
      float4 v = ((const float4*)ehs)[idx];
      short4v o;
      o[0] = (short)f2bf(v.x);
      o[1] = (short)f2bf(v.y);
      o[2] = (short)f2bf(v.z);
      o[3] = (short)f2bf(v.w);
      ((short4v*)A16)[idx] = o;
    }
    return;
  }
  __shared__ float As[8][33];
  __shared__ float Bs[8][100];
  const int bm = blockIdx.x / 3, bn = blockIdx.x % 3;
  const int m0 = bm * 32, n0 = bn * 96;
  const int tr = tid >> 4, tc = tid & 15;

  float acc[2][6];
#pragma unroll
  for (int i = 0; i < 2; i++)
#pragma unroll
    for (int j = 0; j < 6; j++) acc[i][j] = 0.f;

  const int sar = tid >> 3, sak = tid & 7;
  const int sbk = tid / 24, sbc = (tid % 24) * 4;

  for (int k0 = 0; k0 < 256; k0 += 8) {
    float a1 = hidden[(size_t)(m0 + sar) * 256 + k0 + sak];
    float4 b4 = make_float4(0.f, 0.f, 0.f, 0.f);
    if (tid < 192)
      b4 = *(const float4*)(Wcat + (size_t)(k0 + sbk) * 288 + n0 + sbc);
    __syncthreads();
    As[sak][sar] = a1;
    if (tid < 192) *(float4*)&Bs[sbk][sbc] = b4;
    __syncthreads();
#pragma unroll
    for (int k = 0; k < 8; k++) {
      float ar[2], br[6];
#pragma unroll
      for (int i = 0; i < 2; i++) ar[i] = As[k][tr * 2 + i];
#pragma unroll
      for (int j = 0; j < 6; j++) br[j] = Bs[k][tc * 6 + j];
#pragma unroll
      for (int i = 0; i < 2; i++)
#pragma unroll
        for (int j = 0; j < 6; j++) acc[i][j] = fmaf(ar[i], br[j], acc[i][j]);
    }
  }

#pragma unroll
  for (int i = 0; i < 2; i++) {
    const int row = m0 + tr * 2 + i;
    float* Crow = offaw + (size_t)row * 288 + n0 + tc * 6;
#pragma unroll
    for (int j = 0; j < 6; j += 2) {
      float2 o;
      o.x = acc[i][j + 0] + bcat[n0 + tc * 6 + j + 0];
      o.y = acc[i][j + 1] + bcat[n0 + tc * 6 + j + 1];
      *(float2*)(Crow + j) = o;
    }
  }
}

// ---------------------------------------------------------------------------
// Value GEMM, all-bf16, global_load_lds staging (m97 structure). Proven R13.
// ---------------------------------------------------------------------------
__global__ __launch_bounds__(256) void gemm_value_g16(
    const u16* __restrict__ A16, const u16* __restrict__ Wt,
    const float* __restrict__ bias, u16* __restrict__ C) {
  const int m0 = blockIdx.y * 128, n0 = blockIdx.x * 128;
  __shared__ u16 smem[16384];   // 32 KiB
  u16* const As = smem;
  u16* const Bs = smem + 8192;
  const int tid = threadIdx.x, lane = tid & 63, w = tid >> 6;
  const int wrow = w >> 1, wcol = w & 1;

  f32x4 acc[4][4];
#pragma unroll
  for (int i = 0; i < 4; i++)
#pragma unroll
    for (int j = 0; j < 4; j++) acc[i][j] = (f32x4){0.f, 0.f, 0.f, 0.f};

#pragma unroll
  for (int t = 0; t < 4; t++) {
    const int k0 = t * 64;
#pragma unroll
    for (int c = 0; c < 4; c++) {
      const int G = c * 256 + w * 64 + lane;
      const int row = G >> 3, gr = G & 7;
      const int ksw = (gr * 8) ^ ((row & 7) * 8);
      __builtin_amdgcn_global_load_lds(
          A16 + (size_t)(m0 + row) * 256 + k0 + ksw,
          As + c * 2048 + w * 512, 16, 0, 0);
      __builtin_amdgcn_global_load_lds(
          Wt + (size_t)(n0 + row) * 256 + k0 + ksw,
          Bs + c * 2048 + w * 512, 16, 0, 0);
    }
    __syncthreads();

#pragma unroll
    for (int kk = 0; kk < 64; kk += 32) {
      const int kb = kk + ((lane >> 4) << 3);
      short8 af[4], bfr[4];
#pragma unroll
      for (int i = 0; i < 4; i++) {
        const int row = wrow * 64 + i * 16 + (lane & 15);
        af[i] = *(const short8*)&As[row * 64 + (kb ^ ((row & 7) * 8))];
      }
#pragma unroll
      for (int j = 0; j < 4; j++) {
        const int nr = wcol * 64 + j * 16 + (lane & 15);
        bfr[j] = *(const short8*)&Bs[nr * 64 + (kb ^ ((nr & 7) * 8))];
      }
#pragma unroll
      for (int i = 0; i < 4; i++)
#pragma unroll
        for (int j = 0; j < 4; j++)
          acc[i][j] = mfma16(af[i], bfr[j], acc[i][j]);
    }
    __syncthreads();
  }

  u16* const Cs = smem;
#pragma unroll
  for (int i = 0; i < 4; i++) {
#pragma unroll
    for (int j = 0; j < 4; j++) {
      const int col = wcol * 64 + j * 16 + (lane & 15);
      const float bc = bias[n0 + col];
#pragma unroll
      for (int r = 0; r < 4; r++) {
        const int row = wrow * 64 + i * 16 + ((lane >> 4) << 2) + r;
        Cs[row * 128 + (col ^ ((row & 7) * 8))] = f2bf(acc[i][j][r] + bc);
      }
    }
  }
  __syncthreads();
#pragma unroll
  for (int p = 0; p < 8; p++) {
    const int row = (tid >> 4) + p * 16;
    const int g = (tid & 15) * 8;
    *(short8*)(C + (size_t)(m0 + row) * 256 + n0 + g) =
        *(const short8*)&Cs[row * 128 + (g ^ ((row & 7) * 8))];
  }
}

// ---------------------------------------------------------------------------
// Fallback value GEMM (R9 bk32) if ws too small.
// ---------------------------------------------------------------------------
__global__ __launch_bounds__(256) void gemm_value_bk32(
    const float* __restrict__ A, const u16* __restrict__ Wt,
    const float* __restrict__ bias, u16* __restrict__ C) {
  const int m0 = blockIdx.y * 128, n0 = blockIdx.x * 128;
  __shared__ u16 smem[16384];
  u16* As = smem;
  u16* Bs = smem + 4096;
  const int tid = threadIdx.x, lane = tid & 63, w = tid >> 6;
  const int wrow = w >> 1, wcol = w & 1;
  const int ar = tid >> 3, ac4 = (tid & 7) * 4;
  const int bn = tid >> 1, bc16 = (tid & 1) * 16;
  const int bswz = (bn & 3) * 8;

  f32x4 acc[4][4];
#pragma unroll
  for (int i = 0; i < 4; i++)
#pragma unroll
    for (int j = 0; j < 4; j++) acc[i][j] = (f32x4){0.f, 0.f, 0.f, 0.f};

  float4 av[4];
  short8 bv[2];
#pragma unroll
  for (int p = 0; p < 4; p++)
    av[p] = *(const float4*)(A + (size_t)(m0 + ar + p * 32) * 256 + ac4);
#pragma unroll
  for (int j = 0; j < 2; j++)
    bv[j] = *(const short8*)(Wt + (size_t)(n0 + bn) * 256 + ((bc16 + 8 * j) ^ bswz));

#pragma unroll
  for (int t = 0; t < 8; t++) {
    __syncthreads();
#pragma unroll
    for (int p = 0; p < 4; p++) {
      const int row = ar + p * 32;
      short4v sv;
      sv[0] = (short)f2bf(av[p].x);
      sv[1] = (short)f2bf(av[p].y);
      sv[2] = (short)f2bf(av[p].z);
      sv[3] = (short)f2bf(av[p].w);
      *(short4v*)&As[row * 32 + (ac4 ^ ((row & 3) * 8))] = sv;
    }
#pragma unroll
    for (int j = 0; j < 2; j++)
      *(short8*)&Bs[bn * 32 + bc16 + 8 * j] = bv[j];
    __syncthreads();

    if (t < 7) {
      const int k0 = (t + 1) * 32;
#pragma unroll
      for (int p = 0; p < 4; p++)
        av[p] = *(const float4*)(A + (size_t)(m0 + ar + p * 32) * 256 + k0 + ac4);
#pragma unroll
      for (int j = 0; j < 2; j++)
        bv[j] = *(const short8*)(Wt + (size_t)(n0 + bn) * 256 + k0 + ((bc16 + 8 * j) ^ bswz));
    }

    const int kb = (lane >> 4) * 8;
    short8 af[4], bfr[4];
#pragma unroll
    for (int i = 0; i < 4; i++) {
      const int row = wrow * 64 + i * 16 + (lane & 15);
      af[i] = *(const short8*)&As[row * 32 + (kb ^ ((row & 3) * 8))];
    }
#pragma unroll
    for (int j = 0; j < 4; j++) {
      const int nr = wcol * 64 + j * 16 + (lane & 15);
      bfr[j] = *(const short8*)&Bs[nr * 32 + (kb ^ ((nr & 3) * 8))];
    }
#pragma unroll
    for (int i = 0; i < 4; i++)
#pragma unroll
      for (int j = 0; j < 4; j++)
        acc[i][j] = mfma16(af[i], bfr[j], acc[i][j]);
  }

  __syncthreads();
  u16* Cs = smem;
#pragma unroll
  for (int i = 0; i < 4; i++) {
#pragma unroll
    for (int j = 0; j < 4; j++) {
      const int col = wcol * 64 + j * 16 + (lane & 15);
      const float bc = bias[n0 + col];
#pragma unroll
      for (int r = 0; r < 4; r++) {
        const int row = wrow * 64 + i * 16 + ((lane >> 4) << 2) + r;
        Cs[row * 128 + (col ^ ((row & 7) * 8))] = f2bf(acc[i][j][r] + bc);
      }
    }
  }
  __syncthreads();
#pragma unroll
  for (int p = 0; p < 8; p++) {
    const int row = (tid >> 4) + p * 16;
    const int g = (tid & 15) * 8;
    *(short8*)(C + (size_t)(m0 + row) * 256 + n0 + g) =
        *(const short8*)&Cs[row * 128 + (g ^ ((row & 7) * 8))];
  }
}

// ---------------------------------------------------------------------------
// fp32 GEMM standalone (fallback path only).
// ---------------------------------------------------------------------------
__global__ __launch_bounds__(256) void gemm_f32(
    const float* __restrict__ A, const float* __restrict__ W,
    const float* __restrict__ bias, float* __restrict__ C,
    int M, int N, int K) {
  __shared__ float As[8][132];
  __shared__ float Bs[8][132];
  const int tid = threadIdx.x;
  const int bm = blockIdx.y, bn = blockIdx.x;
  const int tr = tid >> 4, tc = tid & 15;

  float acc[8][8];
#pragma unroll
  for (int i = 0; i < 8; i++)
#pragma unroll
    for (int j = 0; j < 8; j++) acc[i][j] = 0.f;

  int arow = bm * 128 + (tid >> 1);
  int arow_c = arow < M ? arow : (M - 1);
  const float* Aptr = A + (size_t)arow_c * K + ((tid & 1) << 2);
  int bcol = bn * 128 + ((tid & 31) << 2);
  const bool bvalid = bcol < N;
  const float* Wptr = W + (size_t)(tid >> 5) * N + bcol;

  for (int k0 = 0; k0 < K; k0 += 8) {
    float4 av = *(const float4*)(Aptr + k0);
    float4 bv = bvalid ? *(const float4*)(Wptr + (size_t)k0 * N)
                       : make_float4(0.f, 0.f, 0.f, 0.f);
    __syncthreads();
    As[(tid & 1) * 4 + 0][tid >> 1] = av.x;
    As[(tid & 1) * 4 + 1][tid >> 1] = av.y;
    As[(tid & 1) * 4 + 2][tid >> 1] = av.z;
    As[(tid & 1) * 4 + 3][tid >> 1] = av.w;
    *(float4*)&Bs[tid >> 5][(tid & 31) << 2] = bv;
    __syncthreads();
#pragma unroll
    for (int k = 0; k < 8; k++) {
      float ar[8], br[8];
      *(float4*)&ar[0] = *(const float4*)&As[k][tr * 8];
      *(float4*)&ar[4] = *(const float4*)&As[k][tr * 8 + 4];
      *(float4*)&br[0] = *(const float4*)&Bs[k][tc * 8];
      *(float4*)&br[4] = *(const float4*)&Bs[k][tc * 8 + 4];
#pragma unroll
      for (int i = 0; i < 8; i++)
#pragma unroll
        for (int j = 0; j < 8; j++) acc[i][j] = fmaf(ar[i], br[j], acc[i][j]);
    }
  }

#pragma unroll
  for (int i = 0; i < 8; i++) {
    int row = bm * 128 + tr * 8 + i;
    if (row >= M) continue;
    float* Crow = C + (size_t)row * N;
#pragma unroll
    for (int j = 0; j < 8; j += 4) {
      int col = bn * 128 + tc * 8 + j;
      if (col < N) {
        float4 o;
        o.x = acc[i][j + 0] + bias[col + 0];
        o.y = acc[i][j + 1] + bias[col + 1];
        o.z = acc[i][j + 2] + bias[col + 2];
        o.w = acc[i][j + 3] + bias[col + 3];
        *(float4*)(Crow + col) = o;
      }
    }
  }
}

// ---------------------------------------------------------------------------
// Branch-free sampling, 4 channels/lane, 1 query/wave, XCD swizzle (proven R16).
// ---------------------------------------------------------------------------
__global__ __launch_bounds__(256) void ms_deform_fused(
    const u16* __restrict__ value, const float* __restrict__ offaw,
    const float* __restrict__ refp, u16* __restrict__ attn_out) {
  const int P = blockIdx.x & 7;
  const int t = blockIdx.x >> 3;
  int bq0;
  if (t < 150) bq0 = P * 600 + t * 4;
  else bq0 = 4800 + (P * 2 + (t - 150)) * 4;
  const int q_local = threadIdx.x >> 6;
  const int bq = bq0 + q_local;
  const int h = (threadIdx.x >> 3) & 7;
  const int d4 = (threadIdx.x & 7) * 4;
  u16* outp = attn_out + (size_t)bq * 256 + h * 32 + d4;
  if (bq >= 4800) {
    short4v z = {0, 0, 0, 0};
    *(short4v*)outp = z;
    return;
  }
  const int b = bq / 300;
  const float* row = offaw + (size_t)bq * 288;

  float lg[12];
#pragma unroll
  for (int j = 0; j < 12; j++) lg[j] = row[192 + h * 12 + j];
  float m = lg[0];
#pragma unroll
  for (int j = 1; j < 12; j++) m = fmaxf(m, lg[j]);
  float s = 0.f;
#pragma unroll
  for (int j = 0; j < 12; j++) { lg[j] = __expf(lg[j] - m); s += lg[j]; }
  const float inv = 1.f / s;

  const int lvlW[3] = {80, 40, 20};
  const int lvlS[3] = {0, 6400, 8000};
  const float* ref = refp + (size_t)bq * 12;
  float acc0 = 0.f, acc1 = 0.f, acc2 = 0.f, acc3 = 0.f;

#pragma unroll
  for (int l = 0; l < 3; l++) {
    const int Ws = lvlW[l];
    const float r0 = ref[l * 4 + 0], r1 = ref[l * 4 + 1];
    const float r2 = ref[l * 4 + 2], r3 = ref[l * 4 + 3];
    const u16* vbase = value + ((size_t)(b * 8400 + lvlS[l]) * 256) + h * 32 + d4;
#pragma unroll
    for (int p = 0; p < 4; p++) {
      const float ox = row[h * 24 + l * 8 + p * 2 + 0];
      const float oy = row[h * 24 + l * 8 + p * 2 + 1];
      const float x = (r0 + ox * 0.125f * r2) * (float)Ws - 0.5f;
      const float y = (r1 + oy * 0.125f * r3) * (float)Ws - 0.5f;
      const float x0f = floorf(x), y0f = floorf(y);
      const float wx = x - x0f, wy = y - y0f;
      const int x0 = (int)x0f, y0 = (int)y0f;
      const int x0c = min(max(x0, 0), Ws - 1), x1c = min(max(x0 + 1, 0), Ws - 1);
      const int y0c = min(max(y0, 0), Ws - 1), y1c = min(max(y0 + 1, 0), Ws - 1);
      const float fx0 = ((unsigned)x0 < (unsigned)Ws) ? 1.f : 0.f;
      const float fx1 = ((unsigned)(x0 + 1) < (unsigned)Ws) ? 1.f : 0.f;
      const float fy0 = ((unsigned)y0 < (unsigned)Ws) ? 1.f : 0.f;
      const float fy1 = ((unsigned)(y0 + 1) < (unsigned)Ws) ? 1.f : 0.f;
      const short4v v00 = *(const short4v*)(vbase + (size_t)(y0c * Ws + x0c) * 256);
      const short4v v01 = *(const short4v*)(vbase + (size_t)(y0c * Ws + x1c) * 256);
      const short4v v10 = *(const short4v*)(vbase + (size_t)(y1c * Ws + x0c) * 256);
      const short4v v11 = *(const short4v*)(vbase + (size_t)(y1c * Ws + x1c) * 256);
      const float pw = lg[l * 4 + p] * inv;
      const float w00 = (1.f - wx) * (1.f - wy) * fy0 * fx0 * pw;
      const float w01 = wx * (1.f - wy) * fy0 * fx1 * pw;
      const float w10 = (1.f - wx) * wy * fy1 * fx0 * pw;
      const float w11 = wx * wy * fy1 * fx1 * pw;
      acc0 = fmaf(w00, bf2f((u16)v00[0]), acc0);
      acc1 = fmaf(w00, bf2f((u16)v00[1]), acc1);
      acc2 = fmaf(w00, bf2f((u16)v00[2]), acc2);
      acc3 = fmaf(w00, bf2f((u16)v00[3]), acc3);
      acc0 = fmaf(w01, bf2f((u16)v01[0]), acc0);
      acc1 = fmaf(w01, bf2f((u16)v01[1]), acc1);
      acc2 = fmaf(w01, bf2f((u16)v01[2]), acc2);
      acc3 = fmaf(w01, bf2f((u16)v01[3]), acc3);
      acc0 = fmaf(w10, bf2f((u16)v10[0]), acc0);
      acc1 = fmaf(w10, bf2f((u16)v10[1]), acc1);
      acc2 = fmaf(w10, bf2f((u16)v10[2]), acc2);
      acc3 = fmaf(w10, bf2f((u16)v10[3]), acc3);
      acc0 = fmaf(w11, bf2f((u16)v11[0]), acc0);
      acc1 = fmaf(w11, bf2f((u16)v11[1]), acc1);
      acc2 = fmaf(w11, bf2f((u16)v11[2]), acc2);
      acc3 = fmaf(w11, bf2f((u16)v11[3]), acc3);
    }
  }
  short4v o;
  o[0] = (short)f2bf(acc0);
  o[1] = (short)f2bf(acc1);
  o[2] = (short)f2bf(acc2);
  o[3] = (short)f2bf(acc3);
  *(short4v*)outp = o;
}

// ---------------------------------------------------------------------------
// Out-proj streaming GEMM (proven R6).
// ---------------------------------------------------------------------------
__global__ __launch_bounds__(256) void gemm_out_stream(
    const u16* __restrict__ A, const u16* __restrict__ Wt,
    const float* __restrict__ bias, float* __restrict__ C) {
  const int tid = threadIdx.x, lane = tid & 63, w = tid >> 6;
  const int m0 = (blockIdx.x * 2 + (w >> 1)) * 64;
  const int n0 = (w & 1) * 128;
  const int r16 = lane & 15, kq = lane >> 4, kh8 = kq * 8;

  f32x4 acc[4][8];
#pragma unroll
  for (int i = 0; i < 4; i++)
#pragma unroll
    for (int j = 0; j < 8; j++) acc[i][j] = (f32x4){0.f, 0.f, 0.f, 0.f};

  const u16* ab = A + (size_t)(m0 + r16) * 256 + kh8;
  const u16* bb = Wt + (size_t)(n0 + r16) * 256 + kh8;

#pragma unroll 2
  for (int ks = 0; ks < 8; ks++) {
    const int kk = ks * 32;
    short8 bfr[8], afr[4];
#pragma unroll
    for (int j = 0; j < 8; j++)
      bfr[j] = *(const short8*)(bb + (size_t)(j * 16) * 256 + kk);
#pragma unroll
    for (int i = 0; i < 4; i++)
      afr[i] = *(const short8*)(ab + (size_t)(i * 16) * 256 + kk);
#pragma unroll
    for (int i = 0; i < 4; i++)
#pragma unroll
      for (int j = 0; j < 8; j++)
        acc[i][j] = mfma16(afr[i], bfr[j], acc[i][j]);
  }

  if (m0 >= 4800) return;
#pragma unroll
  for (int i = 0; i < 4; i++)
#pragma unroll
    for (int j = 0; j < 8; j++) {
      const int col = n0 + j * 16 + r16;
      const float bc = bias[col];
#pragma unroll
      for (int r = 0; r < 4; r++) {
        const int row = m0 + i * 16 + kq * 4 + r;
        C[(size_t)row * 256 + col] = acc[i][j][r] + bc;
      }
    }
}

extern "C" void kernel_launch(void* const* d_in, const int* in_sizes, int n_in,
                              void* d_out, int out_size, void* d_ws, size_t ws_size,
                              hipStream_t stream) {
  const float* hidden = (const float*)d_in[0];
  const float* ehs    = (const float*)d_in[1];
  const float* refp   = (const float*)d_in[2];
  const float* vw     = (const float*)d_in[3];
  const float* vb     = (const float*)d_in[4];
  const float* offw   = (const float*)d_in[5];
  const float* offb   = (const float*)d_in[6];
  const float* attnw  = (const float*)d_in[7];
  const float* attnb  = (const float*)d_in[8];
  const float* outw   = (const float*)d_in[9];
  const float* outb   = (const float*)d_in[10];
  float* out = (float*)d_out;

  u16* value = (u16*)d_ws;                 // 34406400 u16
  u16* attn  = value + 34406400;           // 1245184 u16
  u16* WtV   = attn + 1245184;             // 65536
  u16* outwT = WtV + 65536;                // 65536
  float* Wcat  = (float*)(outwT + 65536);  // 73728 f32
  float* bcat  = Wcat + 73728;             // 512
  float* offaw = bcat + 512;               // 1382400
  u16* A16 = (u16*)(offaw + 1382400);      // 34406400 u16
  const size_t need = (size_t)((char*)(A16 + 34406400) - (char*)d_ws);

  prep_weights<<<288, 256, 0, stream>>>(vw, offw, attnw, offb, attnb, outw,
                                        WtV, outwT, Wcat, bcat);
  if (ws_size >= need) {
    fat_cvt_off2<<<NOFFB + NCVT, 256, 0, stream>>>(ehs, A16, hidden, Wcat, bcat, offaw);
    gemm_value_g16<<<dim3(2, 1050), 256, 0, stream>>>(A16, WtV, vb, value);
  } else {
    gemm_f32<<<dim3(3, 38), 256, 0, stream>>>(hidden, Wcat, bcat, offaw, 4800, 288, 256);
    gemm_value_bk32<<<dim3(2, 1050), 256, 0, stream>>>(ehs, WtV, vb, value);
  }
  ms_deform_fused<<<1216, 256, 0, stream>>>(value, offaw, refp, attn);
  gemm_out_stream<<<38, 256, 0, stream>>>(attn, outwT, outb, out);
}

// Round 19
// 118.891 us; speedup vs baseline: 1.0982x; 1.0838x over previous
//
#include <hip/hip_runtime.h>
#include <math.h>

typedef unsigned short u16;
typedef __attribute__((ext_vector_type(8))) short short8;
typedef __attribute__((ext_vector_type(4))) short short4v;
typedef __attribute__((ext_vector_type(4))) float f32x4;

static __device__ __forceinline__ u16 f2bf(float f) {
  union { float f; unsigned u; } v; v.f = f;
  unsigned u = v.u;
  return (u16)((u + 0x7FFFu + ((u >> 16) & 1u)) >> 16);
}
static __device__ __forceinline__ float bf2f(u16 u) {
  union { unsigned u; float f; } v; v.u = ((unsigned)u) << 16;
  return v.f;
}
static __device__ __forceinline__ unsigned cvtpk(float lo, float hi) {
  unsigned r;
  asm("v_cvt_pk_bf16_f32 %0, %1, %2" : "=v"(r) : "v"(lo), "v"(hi));
  return r;
}
static __device__ __forceinline__ f32x4 mfma16(short8 a, short8 b, f32x4 c) {
  return __builtin_amdgcn_mfma_f32_16x16x32_bf16(a, b, c, 0, 0, 0);
}

// ---------------------------------------------------------------------------
// prep: WtV/outwT bf16 transposed [n][k]; Wcat f32 (256x288) + bcat. (proven)
// ---------------------------------------------------------------------------
__global__ void prep_weights(const float* __restrict__ vw,
                             const float* __restrict__ offw, const float* __restrict__ attnw,
                             const float* __restrict__ offb, const float* __restrict__ attnb,
                             const float* __restrict__ outw,
                             u16* __restrict__ WtV, u16* __restrict__ outwT,
                             float* __restrict__ Wcat, float* __restrict__ bcat) {
  int idx = blockIdx.x * 256 + threadIdx.x;  // grid 288 -> 73728
  if (idx < 65536) {
    int n = idx >> 8, k = idx & 255;
    WtV[idx] = f2bf(vw[k * 256 + n]);
    outwT[idx] = f2bf(outw[k * 256 + n]);
  }
  if (idx < 73728) {
    int kk = idx / 288, nn = idx % 288;
    Wcat[idx] = (nn < 192) ? offw[kk * 192 + nn] : attnw[kk * 96 + (nn - 192)];
  }
  if (idx < 288) bcat[idx] = (idx < 192) ? offb[idx] : attnb[idx - 192];
}

// ---------------------------------------------------------------------------
// Fat kernel v4: blocks [0,450) = offsets fp32 GEMM (proven R16 32x96 body);
// blocks [450,2550) = value GEMM reading ehs f32 DIRECTLY:
//   A staged raw f32 via global_load_lds (16B granules, source pre-swizzled
//   g^(row&7), linear dest); fragment = 2x ds_read_b128 + cvt_pk to bf16.
//   B staging/swizzle/MFMA/epilogue byte-identical to proven R13 g16 kernel.
// Removes the 137.6 MB A16 round-trip (convert kernel deleted).
// LDS: A f32 [128][64] = 32KB + B bf16 [128][64] = 16KB; epilogue reuses 32KB.
// ---------------------------------------------------------------------------
#define NOFFB 450
__global__ __launch_bounds__(256) void fat_off_value(
    const float* __restrict__ ehs, const u16* __restrict__ WtV,
    const float* __restrict__ vbias, u16* __restrict__ value,
    const float* __restrict__ hidden, const float* __restrict__ Wcat,
    const float* __restrict__ bcat, float* __restrict__ offaw) {
  __shared__ __align__(16) u16 smem[24576];  // 48 KiB
  const int tid = threadIdx.x;

  if (blockIdx.x < NOFFB) {
    // ---------------- offsets fp32 GEMM, 32x96 tile (proven R16) ----------
    float* As = (float*)smem;            // [8][33]
    float* Bs = As + 8 * 33;             // [8][100]
    const int bm = blockIdx.x / 3, bn = blockIdx.x % 3;
    const int m0 = bm * 32, n0 = bn * 96;
    const int tr = tid >> 4, tc = tid & 15;

    float acc[2][6];
#pragma unroll
    for (int i = 0; i < 2; i++)
#pragma unroll
      for (int j = 0; j < 6; j++) acc[i][j] = 0.f;

    const int sar = tid >> 3, sak = tid & 7;
    const int sbk = tid / 24, sbc = (tid % 24) * 4;

    for (int k0 = 0; k0 < 256; k0 += 8) {
      float a1 = hidden[(size_t)(m0 + sar) * 256 + k0 + sak];
      float4 b4 = make_float4(0.f, 0.f, 0.f, 0.f);
      if (tid < 192)
        b4 = *(const float4*)(Wcat + (size_t)(k0 + sbk) * 288 + n0 + sbc);
      __syncthreads();
      As[sak * 33 + sar] = a1;
      if (tid < 192) *(float4*)&Bs[sbk * 100 + sbc] = b4;
      __syncthreads();
#pragma unroll
      for (int k = 0; k < 8; k++) {
        float ar[2], br[6];
#pragma unroll
        for (int i = 0; i < 2; i++) ar[i] = As[k * 33 + tr * 2 + i];
#pragma unroll
        for (int j = 0; j < 6; j++) br[j] = Bs[k * 100 + tc * 6 + j];
#pragma unroll
        for (int i = 0; i < 2; i++)
#pragma unroll
          for (int j = 0; j < 6; j++) acc[i][j] = fmaf(ar[i], br[j], acc[i][j]);
      }
    }
#pragma unroll
    for (int i = 0; i < 2; i++) {
      const int row = m0 + tr * 2 + i;
      float* Crow = offaw + (size_t)row * 288 + n0 + tc * 6;
#pragma unroll
      for (int j = 0; j < 6; j += 2) {
        float2 o;
        o.x = acc[i][j + 0] + bcat[n0 + tc * 6 + j + 0];
        o.y = acc[i][j + 1] + bcat[n0 + tc * 6 + j + 1];
        *(float2*)(Crow + j) = o;
      }
    }
    return;
  }

  // ---------------- value GEMM, A f32 direct ----------------
  const int vb_id = blockIdx.x - NOFFB;      // 0..2099
  const int m0 = (vb_id >> 1) * 128;
  const int n0 = (vb_id & 1) * 128;
  const int lane = tid & 63, w = tid >> 6;
  const int wrow = w >> 1, wcol = w & 1;
  float* const Af = (float*)smem;            // [128][64] f32 (32 KiB)
  u16* const Bs = smem + 16384;              // [128][64] bf16 (16 KiB)

  f32x4 acc[4][4];
#pragma unroll
  for (int i = 0; i < 4; i++)
#pragma unroll
    for (int j = 0; j < 4; j++) acc[i][j] = (f32x4){0.f, 0.f, 0.f, 0.f};

#pragma unroll
  for (int t = 0; t < 4; t++) {
    const int k0 = t * 64;
    // A: 2048 granules of 16B (4 f32); LDS[row][g] = A[row][g^(row&7)]
#pragma unroll
    for (int c = 0; c < 8; c++) {
      const int G = c * 256 + w * 64 + lane;
      const int row = G >> 4, g = G & 15;
      const int gs = g ^ (row & 7);
      __builtin_amdgcn_global_load_lds(
          (const u16*)(ehs + (size_t)(m0 + row) * 256 + k0 + gs * 4),
          (u16*)(Af) + G * 8, 16, 0, 0);
    }
    // B: 1024 granules of 8 u16 (byte-identical to proven g16)
#pragma unroll
    for (int c = 0; c < 4; c++) {
      const int G = c * 256 + w * 64 + lane;
      const int row = G >> 3, gr = G & 7;
      const int ksw = (gr * 8) ^ ((row & 7) * 8);
      __builtin_amdgcn_global_load_lds(
          WtV + (size_t)(n0 + row) * 256 + k0 + ksw,
          Bs + c * 2048 + w * 512, 16, 0, 0);
    }
    __syncthreads();

#pragma unroll
    for (int kk = 0; kk < 64; kk += 32) {
      const int kb = kk + ((lane >> 4) << 3);  // f32 index within 64
      short8 af[4], bfr[4];
#pragma unroll
      for (int i = 0; i < 4; i++) {
        const int row = wrow * 64 + i * 16 + (lane & 15);
        const int x = (kb >> 2) ^ (row & 7);   // granule of k[kb..kb+4)
        f32x4 lo = *(const f32x4*)&Af[row * 64 + x * 4];
        f32x4 hi = *(const f32x4*)&Af[row * 64 + (x ^ 1) * 4];
        union { unsigned u[4]; short8 s; } tt;
        tt.u[0] = cvtpk(lo[0], lo[1]);
        tt.u[1] = cvtpk(lo[2], lo[3]);
        tt.u[2] = cvtpk(hi[0], hi[1]);
        tt.u[3] = cvtpk(hi[2], hi[3]);
        af[i] = tt.s;
      }
#pragma unroll
      for (int j = 0; j < 4; j++) {
        const int nr = wcol * 64 + j * 16 + (lane & 15);
        bfr[j] = *(const short8*)&Bs[nr * 64 + (kb ^ ((nr & 7) * 8))];
      }
#pragma unroll
      for (int i = 0; i < 4; i++)
#pragma unroll
        for (int j = 0; j < 4; j++)
          acc[i][j] = mfma16(af[i], bfr[j], acc[i][j]);
    }
    __syncthreads();
  }

  // epilogue: LDS repack -> dwordx4 stores (byte-identical to proven g16)
  u16* const Cs = smem;  // 128x128 u16 = 32 KiB
#pragma unroll
  for (int i = 0; i < 4; i++) {
#pragma unroll
    for (int j = 0; j < 4; j++) {
      const int col = wcol * 64 + j * 16 + (lane & 15);
      const float bc = vbias[n0 + col];
#pragma unroll
      for (int r = 0; r < 4; r++) {
        const int row = wrow * 64 + i * 16 + ((lane >> 4) << 2) + r;
        Cs[row * 128 + (col ^ ((row & 7) * 8))] = f2bf(acc[i][j][r] + bc);
      }
    }
  }
  __syncthreads();
#pragma unroll
  for (int p = 0; p < 8; p++) {
    const int row = (tid >> 4) + p * 16;
    const int g = (tid & 15) * 8;
    *(short8*)(value + (size_t)(m0 + row) * 256 + n0 + g) =
        *(const short8*)&Cs[row * 128 + (g ^ ((row & 7) * 8))];
  }
}

// ---------------------------------------------------------------------------
// Branch-free sampling, 4 channels/lane, 1 query/wave, XCD swizzle (proven R16).
// ---------------------------------------------------------------------------
__global__ __launch_bounds__(256) void ms_deform_fused(
    const u16* __restrict__ value, const float* __restrict__ offaw,
    const float* __restrict__ refp, u16* __restrict__ attn_out) {
  const int P = blockIdx.x & 7;
  const int t = blockIdx.x >> 3;
  int bq0;
  if (t < 150) bq0 = P * 600 + t * 4;
  else bq0 = 4800 + (P * 2 + (t - 150)) * 4;
  const int q_local = threadIdx.x >> 6;
  const int bq = bq0 + q_local;
  const int h = (threadIdx.x >> 3) & 7;
  const int d4 = (threadIdx.x & 7) * 4;
  u16* outp = attn_out + (size_t)bq * 256 + h * 32 + d4;
  if (bq >= 4800) {
    short4v z = {0, 0, 0, 0};
    *(short4v*)outp = z;
    return;
  }
  const int b = bq / 300;
  const float* row = offaw + (size_t)bq * 288;

  float lg[12];
#pragma unroll
  for (int j = 0; j < 12; j++) lg[j] = row[192 + h * 12 + j];
  float m = lg[0];
#pragma unroll
  for (int j = 1; j < 12; j++) m = fmaxf(m, lg[j]);
  float s = 0.f;
#pragma unroll
  for (int j = 0; j < 12; j++) { lg[j] = __expf(lg[j] - m); s += lg[j]; }
  const float inv = 1.f / s;

  const int lvlW[3] = {80, 40, 20};
  const int lvlS[3] = {0, 6400, 8000};
  const float* ref = refp + (size_t)bq * 12;
  float acc0 = 0.f, acc1 = 0.f, acc2 = 0.f, acc3 = 0.f;

#pragma unroll
  for (int l = 0; l < 3; l++) {
    const int Ws = lvlW[l];
    const float r0 = ref[l * 4 + 0], r1 = ref[l * 4 + 1];
    const float r2 = ref[l * 4 + 2], r3 = ref[l * 4 + 3];
    const u16* vbase = value + ((size_t)(b * 8400 + lvlS[l]) * 256) + h * 32 + d4;
#pragma unroll
    for (int p = 0; p < 4; p++) {
      const float ox = row[h * 24 + l * 8 + p * 2 + 0];
      const float oy = row[h * 24 + l * 8 + p * 2 + 1];
      const float x = (r0 + ox * 0.125f * r2) * (float)Ws - 0.5f;
      const float y = (r1 + oy * 0.125f * r3) * (float)Ws - 0.5f;
      const float x0f = floorf(x), y0f = floorf(y);
      const float wx = x - x0f, wy = y - y0f;
      const int x0 = (int)x0f, y0 = (int)y0f;
      const int x0c = min(max(x0, 0), Ws - 1), x1c = min(max(x0 + 1, 0), Ws - 1);
      const int y0c = min(max(y0, 0), Ws - 1), y1c = min(max(y0 + 1, 0), Ws - 1);
      const float fx0 = ((unsigned)x0 < (unsigned)Ws) ? 1.f : 0.f;
      const float fx1 = ((unsigned)(x0 + 1) < (unsigned)Ws) ? 1.f : 0.f;
      const float fy0 = ((unsigned)y0 < (unsigned)Ws) ? 1.f : 0.f;
      const float fy1 = ((unsigned)(y0 + 1) < (unsigned)Ws) ? 1.f : 0.f;
      const short4v v00 = *(const short4v*)(vbase + (size_t)(y0c * Ws + x0c) * 256);
      const short4v v01 = *(const short4v*)(vbase + (size_t)(y0c * Ws + x1c) * 256);
      const short4v v10 = *(const short4v*)(vbase + (size_t)(y1c * Ws + x0c) * 256);
      const short4v v11 = *(const short4v*)(vbase + (size_t)(y1c * Ws + x1c) * 256);
      const float pw = lg[l * 4 + p] * inv;
      const float w00 = (1.f - wx) * (1.f - wy) * fy0 * fx0 * pw;
      const float w01 = wx * (1.f - wy) * fy0 * fx1 * pw;
      const float w10 = (1.f - wx) * wy * fy1 * fx0 * pw;
      const float w11 = wx * wy * fy1 * fx1 * pw;
      acc0 = fmaf(w00, bf2f((u16)v00[0]), acc0);
      acc1 = fmaf(w00, bf2f((u16)v00[1]), acc1);
      acc2 = fmaf(w00, bf2f((u16)v00[2]), acc2);
      acc3 = fmaf(w00, bf2f((u16)v00[3]), acc3);
      acc0 = fmaf(w01, bf2f((u16)v01[0]), acc0);
      acc1 = fmaf(w01, bf2f((u16)v01[1]), acc1);
      acc2 = fmaf(w01, bf2f((u16)v01[2]), acc2);
      acc3 = fmaf(w01, bf2f((u16)v01[3]), acc3);
      acc0 = fmaf(w10, bf2f((u16)v10[0]), acc0);
      acc1 = fmaf(w10, bf2f((u16)v10[1]), acc1);
      acc2 = fmaf(w10, bf2f((u16)v10[2]), acc2);
      acc3 = fmaf(w10, bf2f((u16)v10[3]), acc3);
      acc0 = fmaf(w11, bf2f((u16)v11[0]), acc0);
      acc1 = fmaf(w11, bf2f((u16)v11[1]), acc1);
      acc2 = fmaf(w11, bf2f((u16)v11[2]), acc2);
      acc3 = fmaf(w11, bf2f((u16)v11[3]), acc3);
    }
  }
  short4v o;
  o[0] = (short)f2bf(acc0);
  o[1] = (short)f2bf(acc1);
  o[2] = (short)f2bf(acc2);
  o[3] = (short)f2bf(acc3);
  *(short4v*)outp = o;
}

// ---------------------------------------------------------------------------
// Out-proj streaming GEMM (proven R6).
// ---------------------------------------------------------------------------
__global__ __launch_bounds__(256) void gemm_out_stream(
    const u16* __restrict__ A, const u16* __restrict__ Wt,
    const float* __restrict__ bias, float* __restrict__ C) {
  const int tid = threadIdx.x, lane = tid & 63, w = tid >> 6;
  const int m0 = (blockIdx.x * 2 + (w >> 1)) * 64;
  const int n0 = (w & 1) * 128;
  const int r16 = lane & 15, kq = lane >> 4, kh8 = kq * 8;

  f32x4 acc[4][8];
#pragma unroll
  for (int i = 0; i < 4; i++)
#pragma unroll
    for (int j = 0; j < 8; j++) acc[i][j] = (f32x4){0.f, 0.f, 0.f, 0.f};

  const u16* ab = A + (size_t)(m0 + r16) * 256 + kh8;
  const u16* bb = Wt + (size_t)(n0 + r16) * 256 + kh8;

#pragma unroll 2
  for (int ks = 0; ks < 8; ks++) {
    const int kk = ks * 32;
    short8 bfr[8], afr[4];
#pragma unroll
    for (int j = 0; j < 8; j++)
      bfr[j] = *(const short8*)(bb + (size_t)(j * 16) * 256 + kk);
#pragma unroll
    for (int i = 0; i < 4; i++)
      afr[i] = *(const short8*)(ab + (size_t)(i * 16) * 256 + kk);
#pragma unroll
    for (int i = 0; i < 4; i++)
#pragma unroll
      for (int j = 0; j < 8; j++)
        acc[i][j] = mfma16(afr[i], bfr[j], acc[i][j]);
  }

  if (m0 >= 4800) return;
#pragma unroll
  for (int i = 0; i < 4; i++)
#pragma unroll
    for (int j = 0; j < 8; j++) {
      const int col = n0 + j * 16 + r16;
      const float bc = bias[col];
#pragma unroll
      for (int r = 0; r < 4; r++) {
        const int row = m0 + i * 16 + kq * 4 + r;
        C[(size_t)row * 256 + col] = acc[i][j][r] + bc;
      }
    }
}

extern "C" void kernel_launch(void* const* d_in, const int* in_sizes, int n_in,
                              void* d_out, int out_size, void* d_ws, size_t ws_size,
                              hipStream_t stream) {
  const float* hidden = (const float*)d_in[0];
  const float* ehs    = (const float*)d_in[1];
  const float* refp   = (const float*)d_in[2];
  const float* vw     = (const float*)d_in[3];
  const float* vb     = (const float*)d_in[4];
  const float* offw   = (const float*)d_in[5];
  const float* offb   = (const float*)d_in[6];
  const float* attnw  = (const float*)d_in[7];
  const float* attnb  = (const float*)d_in[8];
  const float* outw   = (const float*)d_in[9];
  const float* outb   = (const float*)d_in[10];
  float* out = (float*)d_out;

  u16* value = (u16*)d_ws;                 // 34406400 u16
  u16* attn  = value + 34406400;           // 1245184 u16
  u16* WtV   = attn + 1245184;             // 65536
  u16* outwT = WtV + 65536;                // 65536
  float* Wcat  = (float*)(outwT + 65536);  // 73728 f32
  float* bcat  = Wcat + 73728;             // 512
  float* offaw = bcat + 512;               // 1382400

  prep_weights<<<288, 256, 0, stream>>>(vw, offw, attnw, offb, attnb, outw,
                                        WtV, outwT, Wcat, bcat);
  fat_off_value<<<NOFFB + 2100, 256, 0, stream>>>(ehs, WtV, vb, value,
                                                  hidden, Wcat, bcat, offaw);
  ms_deform_fused<<<1216, 256, 0, stream>>>(value, offaw, refp, attn);
  gemm_out_stream<<<38, 256, 0, stream>>>(attn, outwT, outb, out);
}

// Round 20
// 118.221 us; speedup vs baseline: 1.1044x; 1.0057x over previous
//
#include <hip/hip_runtime.h>
#include <math.h>

typedef unsigned short u16;
typedef __attribute__((ext_vector_type(8))) short short8;
typedef __attribute__((ext_vector_type(4))) short short4v;
typedef __attribute__((ext_vector_type(4))) float f32x4;

static __device__ __forceinline__ u16 f2bf(float f) {
  union { float f; unsigned u; } v; v.f = f;
  unsigned u = v.u;
  return (u16)((u + 0x7FFFu + ((u >> 16) & 1u)) >> 16);
}
static __device__ __forceinline__ float bf2f(u16 u) {
  union { unsigned u; float f; } v; v.u = ((unsigned)u) << 16;
  return v.f;
}
static __device__ __forceinline__ unsigned cvtpk(float lo, float hi) {
  unsigned r;
  asm("v_cvt_pk_bf16_f32 %0, %1, %2" : "=v"(r) : "v"(lo), "v"(hi));
  return r;
}
static __device__ __forceinline__ f32x4 mfma16(short8 a, short8 b, f32x4 c) {
  return __builtin_amdgcn_mfma_f32_16x16x32_bf16(a, b, c, 0, 0, 0);
}

// ---------------------------------------------------------------------------
// prep: WtV/outwT bf16 transposed [n][k]; Wcat f32 (256x288) + bcat. (proven)
// ---------------------------------------------------------------------------
__global__ void prep_weights(const float* __restrict__ vw,
                             const float* __restrict__ offw, const float* __restrict__ attnw,
                             const float* __restrict__ offb, const float* __restrict__ attnb,
                             const float* __restrict__ outw,
                             u16* __restrict__ WtV, u16* __restrict__ outwT,
                             float* __restrict__ Wcat, float* __restrict__ bcat) {
  int idx = blockIdx.x * 256 + threadIdx.x;  // grid 288 -> 73728
  if (idx < 65536) {
    int n = idx >> 8, k = idx & 255;
    WtV[idx] = f2bf(vw[k * 256 + n]);
    outwT[idx] = f2bf(outw[k * 256 + n]);
  }
  if (idx < 73728) {
    int kk = idx / 288, nn = idx % 288;
    Wcat[idx] = (nn < 192) ? offw[kk * 192 + nn] : attnw[kk * 96 + (nn - 192)];
  }
  if (idx < 288) bcat[idx] = (idx < 192) ? offb[idx] : attnb[idx - 192];
}

// ---------------------------------------------------------------------------
// Fat kernel v5: blocks [0,450) = offsets fp32 GEMM (proven R16 32x96 body);
// blocks [450,2550) = value GEMM, f32-A-direct:
//   A: BK=32, f32 [128][32] = 16 KB via global_load_lds (granule swz g^(row&7))
//   B: BK=64, bf16 [128][64] = 16 KB, staged every other step (proven layout)
//   LDS 32 KB total -> 5 blocks/CU (vs R19's 48 KB -> 3; the occupancy fix).
//   8 K-steps of 16 MFMA each; epilogue reuses the 32 KB (proven).
// ---------------------------------------------------------------------------
#define NOFFB 450
__global__ __launch_bounds__(256) void fat_off_value(
    const float* __restrict__ ehs, const u16* __restrict__ WtV,
    const float* __restrict__ vbias, u16* __restrict__ value,
    const float* __restrict__ hidden, const float* __restrict__ Wcat,
    const float* __restrict__ bcat, float* __restrict__ offaw) {
  __shared__ __align__(16) u16 smem[16384];  // 32 KiB
  const int tid = threadIdx.x;

  if (blockIdx.x < NOFFB) {
    // ---------------- offsets fp32 GEMM, 32x96 tile (proven R16) ----------
    float* As = (float*)smem;            // [8][33]
    float* Bsf = As + 8 * 33;            // [8][100]
    const int bm = blockIdx.x / 3, bn = blockIdx.x % 3;
    const int m0 = bm * 32, n0 = bn * 96;
    const int tr = tid >> 4, tc = tid & 15;

    float acc[2][6];
#pragma unroll
    for (int i = 0; i < 2; i++)
#pragma unroll
      for (int j = 0; j < 6; j++) acc[i][j] = 0.f;

    const int sar = tid >> 3, sak = tid & 7;
    const int sbk = tid / 24, sbc = (tid % 24) * 4;

    for (int k0 = 0; k0 < 256; k0 += 8) {
      float a1 = hidden[(size_t)(m0 + sar) * 256 + k0 + sak];
      float4 b4 = make_float4(0.f, 0.f, 0.f, 0.f);
      if (tid < 192)
        b4 = *(const float4*)(Wcat + (size_t)(k0 + sbk) * 288 + n0 + sbc);
      __syncthreads();
      As[sak * 33 + sar] = a1;
      if (tid < 192) *(float4*)&Bsf[sbk * 100 + sbc] = b4;
      __syncthreads();
#pragma unroll
      for (int k = 0; k < 8; k++) {
        float ar[2], br[6];
#pragma unroll
        for (int i = 0; i < 2; i++) ar[i] = As[k * 33 + tr * 2 + i];
#pragma unroll
        for (int j = 0; j < 6; j++) br[j] = Bsf[k * 100 + tc * 6 + j];
#pragma unroll
        for (int i = 0; i < 2; i++)
#pragma unroll
          for (int j = 0; j < 6; j++) acc[i][j] = fmaf(ar[i], br[j], acc[i][j]);
      }
    }
#pragma unroll
    for (int i = 0; i < 2; i++) {
      const int row = m0 + tr * 2 + i;
      float* Crow = offaw + (size_t)row * 288 + n0 + tc * 6;
#pragma unroll
      for (int j = 0; j < 6; j += 2) {
        float2 o;
        o.x = acc[i][j + 0] + bcat[n0 + tc * 6 + j + 0];
        o.y = acc[i][j + 1] + bcat[n0 + tc * 6 + j + 1];
        *(float2*)(Crow + j) = o;
      }
    }
    return;
  }

  // ---------------- value GEMM, A f32 BK=32 / B bf16 BK=64 ----------------
  const int vb_id = blockIdx.x - NOFFB;      // 0..2099
  const int m0 = (vb_id >> 1) * 128;
  const int n0 = (vb_id & 1) * 128;
  const int lane = tid & 63, w = tid >> 6;
  const int wrow = w >> 1, wcol = w & 1;
  const int r16 = lane & 15, kq = lane >> 4;
  float* const Af = (float*)smem;            // [128][32] f32 (16 KiB)
  u16* const Bs = smem + 8192;               // [128][64] bf16 (16 KiB)

  f32x4 acc[4][4];
#pragma unroll
  for (int i = 0; i < 4; i++)
#pragma unroll
    for (int j = 0; j < 4; j++) acc[i][j] = (f32x4){0.f, 0.f, 0.f, 0.f};

#pragma unroll
  for (int t = 0; t < 8; t++) {
    const int k0 = t * 32;  // f32 k base
    // A: 1024 granules of 16B; LDS[row][g] = A[row][g ^ (row&7)]
#pragma unroll
    for (int c = 0; c < 4; c++) {
      const int G = c * 256 + w * 64 + lane;
      const int row = G >> 3, g = G & 7;
      const int gs = g ^ (row & 7);
      __builtin_amdgcn_global_load_lds(
          (const u16*)(ehs + (size_t)(m0 + row) * 256 + k0 + gs * 4),
          (u16*)Af + (size_t)G * 8, 16, 0, 0);
    }
    // B: staged on even steps, BK=64 tile (byte-identical to proven g16)
    if ((t & 1) == 0) {
      const int k0b = (t >> 1) * 64;  // u16 k base
#pragma unroll
      for (int c = 0; c < 4; c++) {
        const int G = c * 256 + w * 64 + lane;
        const int row = G >> 3, gr = G & 7;
        const int ksw = (gr * 8) ^ ((row & 7) * 8);
        __builtin_amdgcn_global_load_lds(
            WtV + (size_t)(n0 + row) * 256 + k0b + ksw,
            Bs + c * 2048 + w * 512, 16, 0, 0);
      }
    }
    __syncthreads();

    const int ka = kq * 8;                    // f32 k within 32 (A)
    const int kb64 = (t & 1) * 32 + kq * 8;   // u16 k within 64 (B)
    short8 af[4], bfr[4];
#pragma unroll
    for (int i = 0; i < 4; i++) {
      const int row = wrow * 64 + i * 16 + r16;
      const int x = (ka >> 2) ^ (row & 7);
      f32x4 lo = *(const f32x4*)&Af[row * 32 + x * 4];
      f32x4 hi = *(const f32x4*)&Af[row * 32 + (x ^ 1) * 4];
      union { unsigned u[4]; short8 s; } tt;
      tt.u[0] = cvtpk(lo[0], lo[1]);
      tt.u[1] = cvtpk(lo[2], lo[3]);
      tt.u[2] = cvtpk(hi[0], hi[1]);
      tt.u[3] = cvtpk(hi[2], hi[3]);
      af[i] = tt.s;
    }
#pragma unroll
    for (int j = 0; j < 4; j++) {
      const int nr = wcol * 64 + j * 16 + r16;
      bfr[j] = *(const short8*)&Bs[nr * 64 + (kb64 ^ ((nr & 7) * 8))];
    }
#pragma unroll
    for (int i = 0; i < 4; i++)
#pragma unroll
      for (int j = 0; j < 4; j++)
        acc[i][j] = mfma16(af[i], bfr[j], acc[i][j]);
    __syncthreads();
  }

  // epilogue: LDS repack -> dwordx4 stores (proven; reuses full 32 KB)
  u16* const Cs = smem;
#pragma unroll
  for (int i = 0; i < 4; i++) {
#pragma unroll
    for (int j = 0; j < 4; j++) {
      const int col = wcol * 64 + j * 16 + r16;
      const float bc = vbias[n0 + col];
#pragma unroll
      for (int r = 0; r < 4; r++) {
        const int row = wrow * 64 + i * 16 + kq * 4 + r;
        Cs[row * 128 + (col ^ ((row & 7) * 8))] = f2bf(acc[i][j][r] + bc);
      }
    }
  }
  __syncthreads();
#pragma unroll
  for (int p = 0; p < 8; p++) {
    const int row = (tid >> 4) + p * 16;
    const int g = (tid & 15) * 8;
    *(short8*)(value + (size_t)(m0 + row) * 256 + n0 + g) =
        *(const short8*)&Cs[row * 128 + (g ^ ((row & 7) * 8))];
  }
}

// ---------------------------------------------------------------------------
// Branch-free sampling, 4 channels/lane, 1 query/wave, XCD swizzle (proven R16).
// ---------------------------------------------------------------------------
__global__ __launch_bounds__(256) void ms_deform_fused(
    const u16* __restrict__ value, const float* __restrict__ offaw,
    const float* __restrict__ refp, u16* __restrict__ attn_out) {
  const int P = blockIdx.x & 7;
  const int t = blockIdx.x >> 3;
  int bq0;
  if (t < 150) bq0 = P * 600 + t * 4;
  else bq0 = 4800 + (P * 2 + (t - 150)) * 4;
  const int q_local = threadIdx.x >> 6;
  const int bq = bq0 + q_local;
  const int h = (threadIdx.x >> 3) & 7;
  const int d4 = (threadIdx.x & 7) * 4;
  u16* outp = attn_out + (size_t)bq * 256 + h * 32 + d4;
  if (bq >= 4800) {
    short4v z = {0, 0, 0, 0};
    *(short4v*)outp = z;
    return;
  }
  const int b = bq / 300;
  const float* row = offaw + (size_t)bq * 288;

  float lg[12];
#pragma unroll
  for (int j = 0; j < 12; j++) lg[j] = row[192 + h * 12 + j];
  float m = lg[0];
#pragma unroll
  for (int j = 1; j < 12; j++) m = fmaxf(m, lg[j]);
  float s = 0.f;
#pragma unroll
  for (int j = 0; j < 12; j++) { lg[j] = __expf(lg[j] - m); s += lg[j]; }
  const float inv = 1.f / s;

  const int lvlW[3] = {80, 40, 20};
  const int lvlS[3] = {0, 6400, 8000};
  const float* ref = refp + (size_t)bq * 12;
  float acc0 = 0.f, acc1 = 0.f, acc2 = 0.f, acc3 = 0.f;

#pragma unroll
  for (int l = 0; l < 3; l++) {
    const int Ws = lvlW[l];
    const float r0 = ref[l * 4 + 0], r1 = ref[l * 4 + 1];
    const float r2 = ref[l * 4 + 2], r3 = ref[l * 4 + 3];
    const u16* vbase = value + ((size_t)(b * 8400 + lvlS[l]) * 256) + h * 32 + d4;
#pragma unroll
    for (int p = 0; p < 4; p++) {
      const float ox = row[h * 24 + l * 8 + p * 2 + 0];
      const float oy = row[h * 24 + l * 8 + p * 2 + 1];
      const float x = (r0 + ox * 0.125f * r2) * (float)Ws - 0.5f;
      const float y = (r1 + oy * 0.125f * r3) * (float)Ws - 0.5f;
      const float x0f = floorf(x), y0f = floorf(y);
      const float wx = x - x0f, wy = y - y0f;
      const int x0 = (int)x0f, y0 = (int)y0f;
      const int x0c = min(max(x0, 0), Ws - 1), x1c = min(max(x0 + 1, 0), Ws - 1);
      const int y0c = min(max(y0, 0), Ws - 1), y1c = min(max(y0 + 1, 0), Ws - 1);
      const float fx0 = ((unsigned)x0 < (unsigned)Ws) ? 1.f : 0.f;
      const float fx1 = ((unsigned)(x0 + 1) < (unsigned)Ws) ? 1.f : 0.f;
      const float fy0 = ((unsigned)y0 < (unsigned)Ws) ? 1.f : 0.f;
      const float fy1 = ((unsigned)(y0 + 1) < (unsigned)Ws) ? 1.f : 0.f;
      const short4v v00 = *(const short4v*)(vbase + (size_t)(y0c * Ws + x0c) * 256);
      const short4v v01 = *(const short4v*)(vbase + (size_t)(y0c * Ws + x1c) * 256);
      const short4v v10 = *(const short4v*)(vbase + (size_t)(y1c * Ws + x0c) * 256);
      const short4v v11 = *(const short4v*)(vbase + (size_t)(y1c * Ws + x1c) * 256);
      const float pw = lg[l * 4 + p] * inv;
      const float w00 = (1.f - wx) * (1.f - wy) * fy0 * fx0 * pw;
      const float w01 = wx * (1.f - wy) * fy0 * fx1 * pw;
      const float w10 = (1.f - wx) * wy * fy1 * fx0 * pw;
      const float w11 = wx * wy * fy1 * fx1 * pw;
      acc0 = fmaf(w00, bf2f((u16)v00[0]), acc0);
      acc1 = fmaf(w00, bf2f((u16)v00[1]), acc1);
      acc2 = fmaf(w00, bf2f((u16)v00[2]), acc2);
      acc3 = fmaf(w00, bf2f((u16)v00[3]), acc3);
      acc0 = fmaf(w01, bf2f((u16)v01[0]), acc0);
      acc1 = fmaf(w01, bf2f((u16)v01[1]), acc1);
      acc2 = fmaf(w01, bf2f((u16)v01[2]), acc2);
      acc3 = fmaf(w01, bf2f((u16)v01[3]), acc3);
      acc0 = fmaf(w10, bf2f((u16)v10[0]), acc0);
      acc1 = fmaf(w10, bf2f((u16)v10[1]), acc1);
      acc2 = fmaf(w10, bf2f((u16)v10[2]), acc2);
      acc3 = fmaf(w10, bf2f((u16)v10[3]), acc3);
      acc0 = fmaf(w11, bf2f((u16)v11[0]), acc0);
      acc1 = fmaf(w11, bf2f((u16)v11[1]), acc1);
      acc2 = fmaf(w11, bf2f((u16)v11[2]), acc2);
      acc3 = fmaf(w11, bf2f((u16)v11[3]), acc3);
    }
  }
  short4v o;
  o[0] = (short)f2bf(acc0);
  o[1] = (short)f2bf(acc1);
  o[2] = (short)f2bf(acc2);
  o[3] = (short)f2bf(acc3);
  *(short4v*)outp = o;
}

// ---------------------------------------------------------------------------
// Out-proj streaming GEMM (proven R6).
// ---------------------------------------------------------------------------
__global__ __launch_bounds__(256) void gemm_out_stream(
    const u16* __restrict__ A, const u16* __restrict__ Wt,
    const float* __restrict__ bias, float* __restrict__ C) {
  const int tid = threadIdx.x, lane = tid & 63, w = tid >> 6;
  const int m0 = (blockIdx.x * 2 + (w >> 1)) * 64;
  const int n0 = (w & 1) * 128;
  const int r16 = lane & 15, kq = lane >> 4, kh8 = kq * 8;

  f32x4 acc[4][8];
#pragma unroll
  for (int i = 0; i < 4; i++)
#pragma unroll
    for (int j = 0; j < 8; j++) acc[i][j] = (f32x4){0.f, 0.f, 0.f, 0.f};

  const u16* ab = A + (size_t)(m0 + r16) * 256 + kh8;
  const u16* bb = Wt + (size_t)(n0 + r16) * 256 + kh8;

#pragma unroll 2
  for (int ks = 0; ks < 8; ks++) {
    const int kk = ks * 32;
    short8 bfr[8], afr[4];
#pragma unroll
    for (int j = 0; j < 8; j++)
      bfr[j] = *(const short8*)(bb + (size_t)(j * 16) * 256 + kk);
#pragma unroll
    for (int i = 0; i < 4; i++)
      afr[i] = *(const short8*)(ab + (size_t)(i * 16) * 256 + kk);
#pragma unroll
    for (int i = 0; i < 4; i++)
#pragma unroll
      for (int j = 0; j < 8; j++)
        acc[i][j] = mfma16(afr[i], bfr[j], acc[i][j]);
  }

  if (m0 >= 4800) return;
#pragma unroll
  for (int i = 0; i < 4; i++)
#pragma unroll
    for (int j = 0; j < 8; j++) {
      const int col = n0 + j * 16 + r16;
      const float bc = bias[col];
#pragma unroll
      for (int r = 0; r < 4; r++) {
        const int row = m0 + i * 16 + kq * 4 + r;
        C[(size_t)row * 256 + col] = acc[i][j][r] + bc;
      }
    }
}

extern "C" void kernel_launch(void* const* d_in, const int* in_sizes, int n_in,
                              void* d_out, int out_size, void* d_ws, size_t ws_size,
                              hipStream_t stream) {
  const float* hidden = (const float*)d_in[0];
  const float* ehs    = (const float*)d_in[1];
  const float* refp   = (const float*)d_in[2];
  const float* vw     = (const float*)d_in[3];
  const float* vb     = (const float*)d_in[4];
  const float* offw   = (const float*)d_in[5];
  const float* offb   = (const float*)d_in[6];
  const float* attnw  = (const float*)d_in[7];
  const float* attnb  = (const float*)d_in[8];
  const float* outw   = (const float*)d_in[9];
  const float* outb   = (const float*)d_in[10];
  float* out = (float*)d_out;

  u16* value = (u16*)d_ws;                 // 34406400 u16
  u16* attn  = value + 34406400;           // 1245184 u16
  u16* WtV   = attn + 1245184;             // 65536
  u16* outwT = WtV + 65536;                // 65536
  float* Wcat  = (float*)(outwT + 65536);  // 73728 f32
  float* bcat  = Wcat + 73728;             // 512
  float* offaw = bcat + 512;               // 1382400

  prep_weights<<<288, 256, 0, stream>>>(vw, offw, attnw, offb, attnb, outw,
                                        WtV, outwT, Wcat, bcat);
  fat_off_value<<<NOFFB + 2100, 256, 0, stream>>>(ehs, WtV, vb, value,
                                                  hidden, Wcat, bcat, offaw);
  ms_deform_fused<<<1216, 256, 0, stream>>>(value, offaw, refp, attn);
  gemm_out_stream<<<38, 256, 0, stream>>>(attn, outwT, outb, out);
}